// Round 7
// baseline (183.818 us; speedup 1.0000x reference)
//
#include <hip/hip_runtime.h>
#include <hip/hip_bf16.h>
#include <stdint.h>

// Multi-head Hyena conv, MFMA flash-attention form, round 7:
//   S^T[m][l] = sum_d1 v[d1,m]*x1[d1,l]       mfma 16x16x32 (K=8 valid)
//   P[l][m]   = S * k[l-m]   (packed-bf16 sliding gate window, zero => causal)
//   O^T[d2][l] += x2 . P^T                    mfma 16x16x32 (full K=32)
// Round-7 change: gate+pack via native packed bf16 (v_cvt_pk_bf16_f32 +
// v_pk_mul_bf16 through __float22bfloat162_rn/__hmul2): 40 -> 16 VALU
// inst/unit; gate window stored as packed bf16x4 (8B) halving gate LDS
// bytes and conflicts. LDS 20.5 -> 18.7 KB (8 blocks/CU).
// Shapes fixed by setup: B=2, D=1024, L=2048, NH=8, H=128.

typedef __attribute__((ext_vector_type(8))) short bf16x8;
typedef __attribute__((ext_vector_type(4))) float f32x4;

#define NHd  8
#define SC   128     // m superchunk staged in LDS
#define GW   192     // gate window entries: l-m spans [l0b-s0-127, l0b-s0+63]

static __device__ __forceinline__ uint32_t pkbf(float a, float b) {
    // pack {bf16(a) lo, bf16(b) hi}; +0x8000 = round-to-nearest (ties away)
    const uint32_t ua = __float_as_uint(a) + 0x8000u;
    const uint32_t ub = __float_as_uint(b) + 0x8000u;
    return __builtin_amdgcn_perm(ub, ua, 0x07060302u);
}

union BU { __hip_bfloat162 h; uint32_t u; };

// round (a,b) to bf16 pair, multiply by packed bf16 gate word g -> packed word
static __device__ __forceinline__ uint32_t gmul(float a, float b, uint32_t g) {
    BU s, gg, r;
    gg.u = g;
    s.h  = __float22bfloat162_rn(make_float2(a, b));
    r.h  = __hmul2(s.h, gg.h);
    return r.u;
}

union U8 { uint32_t u[4]; bf16x8 v; uint4 q; };

__global__ __launch_bounds__(256, 8) void hyena_mfma7_kernel(
    const float* __restrict__ v, const float* __restrict__ kf,
    const float* __restrict__ bias, const float* __restrict__ x1,
    const float* __restrict__ x2, float* __restrict__ out,
    int B, int H, int L)
{
    __shared__ __align__(16) float  ks[2048];           // raw k[h,:] prefix
    __shared__ __align__(16) uint2  gwinb[GW];          // packed bf16x4 gates
    __shared__ __align__(16) ushort vT[2][SC][NHd];     // [b][m][d1] bf16
    __shared__ __align__(16) ushort x2T[2][NHd][136];   // [b][d2][pi(m)] bf16
    __shared__ float sbuf[2][64];                       // skip gate per (b,l)

    const int tid  = threadIdx.x;
    const int h    = blockIdx.x;
    const int l0b  = ((int)gridDim.y - 1 - (int)blockIdx.y) * 64;  // big-l first
    const int nk   = l0b + 64;

    const int lane = tid & 63, wv = tid >> 6;
    const int lq   = lane & 15, quad = lane >> 4;
    const int wb   = wv >> 1;               // batch handled by this wave
    const int wl0  = l0b + (wv & 1) * 32;   // wave's 32-l range start
    const int baseb = (wb * H + h) * NHd * L;

    // ---------- prologue ----------
    for (int i = tid; i < nk; i += 256) ks[i] = kf[h * L + i];

    // xf fragments (mfma1 B operand) straight from global, packed in registers
    bf16x8 xf0 = {}, xf1 = {};
    if (quad == 0) {
        float a0[NHd], a1[NHd];
#pragma unroll
        for (int d1 = 0; d1 < NHd; ++d1) {
            a0[d1] = x1[baseb + d1 * L + wl0 + lq];
            a1[d1] = x1[baseb + d1 * L + wl0 + 16 + lq];
        }
        U8 u0, u1;
#pragma unroll
        for (int j = 0; j < 4; ++j) {
            u0.u[j] = pkbf(a0[2 * j], a0[2 * j + 1]);
            u1.u[j] = pkbf(a1[2 * j], a1[2 * j + 1]);
        }
        xf0 = u0.v; xf1 = u1.v;
    }

    // skip-term gate, both b (threads 0..127)
    if (tid < 128) {
        const int bb = tid >> 6, l = tid & 63;
        const int bs = (bb * H + h) * NHd * L;
        float s = 0.f;
#pragma unroll
        for (int d1 = 0; d1 < NHd; ++d1)
            s += bias[h * NHd + d1] * x1[bs + d1 * L + l0b + l]
                                    * v [bs + d1 * L + l0b + l];
        sbuf[bb][l] = s;
    }

    f32x4 acc0 = {0.f, 0.f, 0.f, 0.f}, acc1 = {0.f, 0.f, 0.f, 0.f};
    const int wlmax = wl0 + 31;
    // in-loop gate window coordinate (s0-independent): e = ebase - c (+/-16)
    const int ebase = 127 + (wv & 1) * 32 + lq - 4 * quad;

    bool gfirst = true;
    uint2 g10c = make_uint2(0u, 0u);       // carried: g10(c+32) == g01(c)

    for (int s0 = 0; s0 < nk; s0 += SC) {
        __syncthreads();   // protects gwinb/vT/x2T from previous iter's readers
        {   // stage vT [b][m][d1] and x2T [b][d2][pi(m)], bf16 via pkbf
            const int bb = tid >> 7, row = tid & 127;
            const int bs = (bb * H + h) * NHd * L;
            const float* vp = v + bs + s0 + row;
            float f[NHd];
#pragma unroll
            for (int d1 = 0; d1 < NHd; ++d1) f[d1] = vp[d1 * L];
            *(uint4*)&vT[bb][row][0] = make_uint4(
                pkbf(f[0], f[1]), pkbf(f[2], f[3]),
                pkbf(f[4], f[5]), pkbf(f[6], f[7]));

            // x2T in pi-permuted order: within each 32-m group, value at m
            // goes to pos 8*((m&15)>>2) + (m&3) + 4*(m>>4)
            const int d2 = row >> 4, ms = (row & 15) * 8;
            const int G = ms & ~31;                       // 32-group base
            const int o = ms & 31;                        // 0,8,16,24
            const int pa = ((o >> 2) & 3) * 8 + (o >> 4) * 4;
            const float* xp = x2 + bs + d2 * L + s0 + ms;
            const float4 q0 = *(const float4*)xp;
            const float4 q1 = *(const float4*)(xp + 4);
            *(uint2*)&x2T[bb][d2][G + pa] =
                make_uint2(pkbf(q0.x, q0.y), pkbf(q0.z, q0.w));
            *(uint2*)&x2T[bb][d2][G + pa + 8] =
                make_uint2(pkbf(q1.x, q1.y), pkbf(q1.z, q1.w));
        }
        // rebuild sliding gate window (packed bf16):
        // gwinb[e] = {bf(k[i]),bf(k[i-1]) | bf(k[i-2]),bf(k[i-3])},
        // i = l0b - s0 - 127 + e; i<0 components -> 0 (causality)
        if (tid < GW - 1) {
            const int i = l0b - s0 - 127 + tid;
            float4 w = {0.f, 0.f, 0.f, 0.f};
            if (i >= 3) {
                w.x = ks[i]; w.y = ks[i - 1]; w.z = ks[i - 2]; w.w = ks[i - 3];
            } else if (i >= 0) {
                w.x = ks[i];
                if (i >= 1) w.y = ks[i - 1];
                if (i >= 2) w.z = ks[i - 2];
            }
            gwinb[tid] = make_uint2(pkbf(w.x, w.y), pkbf(w.z, w.w));
        }
        __syncthreads();

        const int cmax = min(SC, wlmax - s0 + 1);   // wave-uniform, mult of 32
        for (int c = 0; c < cmax; c += 32) {
            // ---- loads first (independent) ----
            bf16x8 av0 = {}, av1 = {};
            if (quad == 0) {
                av0 = *(const bf16x8*)&vT[wb][c + lq][0];
                av1 = *(const bf16x8*)&vT[wb][c + 16 + lq][0];
            }
            const int ge = ebase - c;
            uint2 g10;
            if (gfirst) { g10 = gwinb[ge + 16]; gfirst = false; }
            else        g10 = g10c;
            const uint2 g00 = gwinb[ge];        // S00 & S11
            const uint2 g01 = gwinb[ge - 16];   // S01
            g10c = g01;                         // next iter's g10
            // mfma2 A operand: x2 in pi-permuted k-order
            const bf16x8 ax = *(const bf16x8*)&x2T[wb][lq & 7][c + 8 * quad];

            // ---- mfma1 x4: S^T, 2 m-chunks x 2 l-subtiles ----
            const f32x4 Z = {0.f, 0.f, 0.f, 0.f};
            const f32x4 S00 = __builtin_amdgcn_mfma_f32_16x16x32_bf16(av0, xf0, Z, 0, 0, 0);
            const f32x4 S01 = __builtin_amdgcn_mfma_f32_16x16x32_bf16(av1, xf0, Z, 0, 0, 0);
            const f32x4 S10 = __builtin_amdgcn_mfma_f32_16x16x32_bf16(av0, xf1, Z, 0, 0, 0);
            const f32x4 S11 = __builtin_amdgcn_mfma_f32_16x16x32_bf16(av1, xf1, Z, 0, 0, 0);

            // ---- gate via packed bf16 (cvt_pk + pk_mul), B-frags in regs ----
            U8 p0, p1;
            p0.u[0] = gmul(S00[0], S00[1], g00.x);
            p0.u[1] = gmul(S00[2], S00[3], g00.y);
            p0.u[2] = gmul(S01[0], S01[1], g01.x);
            p0.u[3] = gmul(S01[2], S01[3], g01.y);
            p1.u[0] = gmul(S10[0], S10[1], g10.x);
            p1.u[1] = gmul(S10[2], S10[3], g10.y);
            p1.u[2] = gmul(S11[0], S11[1], g00.x);
            p1.u[3] = gmul(S11[2], S11[3], g00.y);

            // ---- mfma2: O^T += x2 . P^T, full K=32 ----
            acc0 = __builtin_amdgcn_mfma_f32_16x16x32_bf16(ax, p0.v, acc0, 0, 0, 0);
            acc1 = __builtin_amdgcn_mfma_f32_16x16x32_bf16(ax, p1.v, acc1, 0, 0, 0);
        }
    }

    // ---------- epilogue: O^T layout: lane (quad,lq): d2 = 4*quad+r, l = lq ----
    if (quad < 2) {
        const int d2b = 4 * quad;
        const int lA  = wl0 + lq;                 // subtile-0 l; subtile-1 = +16
        const float sb0 = sbuf[wb][(wv & 1) * 32 + lq];
        const float sb1 = sbuf[wb][(wv & 1) * 32 + 16 + lq];
#pragma unroll
        for (int r = 0; r < 4; ++r) {
            const int ro = baseb + (d2b + r) * L + lA;
            out[ro]      = acc0[r] + x2[ro]      * sb0;
            out[ro + 16] = acc1[r] + x2[ro + 16] * sb1;
        }
    }
}

extern "C" void kernel_launch(void* const* d_in, const int* in_sizes, int n_in,
                              void* d_out, int out_size, void* d_ws, size_t ws_size,
                              hipStream_t stream) {
    const float* v    = (const float*)d_in[0];
    const float* k    = (const float*)d_in[1];
    const float* bias = (const float*)d_in[2];
    const float* x1   = (const float*)d_in[3];
    const float* x2   = (const float*)d_in[4];
    float* out = (float*)d_out;

    const int D = in_sizes[2];            // 1024
    const int H = D / NHd;                // 128
    const int L = in_sizes[1] / H;        // 2048
    const int B = in_sizes[0] / (D * L);  // 2

    dim3 grid(H, L / 64);
    hyena_mfma7_kernel<<<grid, 256, 0, stream>>>(v, k, bias, x1, x2, out, B, H, L);
}

// Round 8
// 180.793 us; speedup vs baseline: 1.0167x; 1.0167x over previous
//
#include <hip/hip_runtime.h>
#include <hip/hip_bf16.h>
#include <stdint.h>

// Multi-head Hyena conv, MFMA flash-attention form, round 8:
//   S^T[m][l] = sum_d1 v[d1,m]*x1[d1,l]       mfma 16x16x32 (K=8 valid)
//   P[l][m]   = S * k[l-m]   (packed-bf16 sliding gate window, zero => causal)
//   O^T[d2][l] += x2 . P^T                    mfma 16x16x32 (full K=32)
// Round-8 change: round 7's packed-bf16 gating KEPT, but __launch_bounds__
// back to (256,6). Round 7's (256,8) capped VGPRs at 32 -> scratch spills
// (WRITE_SIZE 16->48.5 MB smoking gun) -> 90.8->116us regression. 40 VGPRs
// at 6 blocks/CU is the proven no-spill point (round 6).
// Shapes fixed by setup: B=2, D=1024, L=2048, NH=8, H=128.

typedef __attribute__((ext_vector_type(8))) short bf16x8;
typedef __attribute__((ext_vector_type(4))) float f32x4;

#define NHd  8
#define SC   128     // m superchunk staged in LDS
#define GW   192     // gate window entries: l-m spans [l0b-s0-127, l0b-s0+63]

static __device__ __forceinline__ uint32_t pkbf(float a, float b) {
    // pack {bf16(a) lo, bf16(b) hi}; +0x8000 = round-to-nearest (ties away)
    const uint32_t ua = __float_as_uint(a) + 0x8000u;
    const uint32_t ub = __float_as_uint(b) + 0x8000u;
    return __builtin_amdgcn_perm(ub, ua, 0x07060302u);
}

union BU { __hip_bfloat162 h; uint32_t u; };

// round (a,b) to bf16 pair, multiply by packed bf16 gate word g -> packed word
static __device__ __forceinline__ uint32_t gmul(float a, float b, uint32_t g) {
    BU s, gg, r;
    gg.u = g;
    s.h  = __float22bfloat162_rn(make_float2(a, b));
    r.h  = __hmul2(s.h, gg.h);
    return r.u;
}

union U8 { uint32_t u[4]; bf16x8 v; uint4 q; };

__global__ __launch_bounds__(256, 6) void hyena_mfma8_kernel(
    const float* __restrict__ v, const float* __restrict__ kf,
    const float* __restrict__ bias, const float* __restrict__ x1,
    const float* __restrict__ x2, float* __restrict__ out,
    int B, int H, int L)
{
    __shared__ __align__(16) float  ks[2048];           // raw k[h,:] prefix
    __shared__ __align__(16) uint2  gwinb[GW];          // packed bf16x4 gates
    __shared__ __align__(16) ushort vT[2][SC][NHd];     // [b][m][d1] bf16
    __shared__ __align__(16) ushort x2T[2][NHd][136];   // [b][d2][pi(m)] bf16
    __shared__ float sbuf[2][64];                       // skip gate per (b,l)

    const int tid  = threadIdx.x;
    const int h    = blockIdx.x;
    const int l0b  = ((int)gridDim.y - 1 - (int)blockIdx.y) * 64;  // big-l first
    const int nk   = l0b + 64;

    const int lane = tid & 63, wv = tid >> 6;
    const int lq   = lane & 15, quad = lane >> 4;
    const int wb   = wv >> 1;               // batch handled by this wave
    const int wl0  = l0b + (wv & 1) * 32;   // wave's 32-l range start
    const int baseb = (wb * H + h) * NHd * L;

    // ---------- prologue ----------
    for (int i = tid; i < nk; i += 256) ks[i] = kf[h * L + i];

    // xf fragments (mfma1 B operand) straight from global, packed in registers
    bf16x8 xf0 = {}, xf1 = {};
    if (quad == 0) {
        float a0[NHd], a1[NHd];
#pragma unroll
        for (int d1 = 0; d1 < NHd; ++d1) {
            a0[d1] = x1[baseb + d1 * L + wl0 + lq];
            a1[d1] = x1[baseb + d1 * L + wl0 + 16 + lq];
        }
        U8 u0, u1;
#pragma unroll
        for (int j = 0; j < 4; ++j) {
            u0.u[j] = pkbf(a0[2 * j], a0[2 * j + 1]);
            u1.u[j] = pkbf(a1[2 * j], a1[2 * j + 1]);
        }
        xf0 = u0.v; xf1 = u1.v;
    }

    // skip-term gate, both b (threads 0..127)
    if (tid < 128) {
        const int bb = tid >> 6, l = tid & 63;
        const int bs = (bb * H + h) * NHd * L;
        float s = 0.f;
#pragma unroll
        for (int d1 = 0; d1 < NHd; ++d1)
            s += bias[h * NHd + d1] * x1[bs + d1 * L + l0b + l]
                                    * v [bs + d1 * L + l0b + l];
        sbuf[bb][l] = s;
    }

    f32x4 acc0 = {0.f, 0.f, 0.f, 0.f}, acc1 = {0.f, 0.f, 0.f, 0.f};
    const int wlmax = wl0 + 31;
    // in-loop gate window coordinate (s0-independent): e = ebase - c (+/-16)
    const int ebase = 127 + (wv & 1) * 32 + lq - 4 * quad;

    bool gfirst = true;
    uint2 g10c = make_uint2(0u, 0u);       // carried: g10(c+32) == g01(c)

    for (int s0 = 0; s0 < nk; s0 += SC) {
        __syncthreads();   // protects gwinb/vT/x2T from previous iter's readers
        {   // stage vT [b][m][d1] and x2T [b][d2][pi(m)], bf16 via pkbf
            const int bb = tid >> 7, row = tid & 127;
            const int bs = (bb * H + h) * NHd * L;
            const float* vp = v + bs + s0 + row;
            float f[NHd];
#pragma unroll
            for (int d1 = 0; d1 < NHd; ++d1) f[d1] = vp[d1 * L];
            *(uint4*)&vT[bb][row][0] = make_uint4(
                pkbf(f[0], f[1]), pkbf(f[2], f[3]),
                pkbf(f[4], f[5]), pkbf(f[6], f[7]));

            // x2T in pi-permuted order: within each 32-m group, value at m
            // goes to pos 8*((m&15)>>2) + (m&3) + 4*(m>>4)
            const int d2 = row >> 4, ms = (row & 15) * 8;
            const int G = ms & ~31;                       // 32-group base
            const int o = ms & 31;                        // 0,8,16,24
            const int pa = ((o >> 2) & 3) * 8 + (o >> 4) * 4;
            const float* xp = x2 + bs + d2 * L + s0 + ms;
            const float4 q0 = *(const float4*)xp;
            const float4 q1 = *(const float4*)(xp + 4);
            *(uint2*)&x2T[bb][d2][G + pa] =
                make_uint2(pkbf(q0.x, q0.y), pkbf(q0.z, q0.w));
            *(uint2*)&x2T[bb][d2][G + pa + 8] =
                make_uint2(pkbf(q1.x, q1.y), pkbf(q1.z, q1.w));
        }
        // rebuild sliding gate window (packed bf16):
        // gwinb[e] = {bf(k[i]),bf(k[i-1]) | bf(k[i-2]),bf(k[i-3])},
        // i = l0b - s0 - 127 + e; i<0 components -> 0 (causality)
        if (tid < GW - 1) {
            const int i = l0b - s0 - 127 + tid;
            float4 w = {0.f, 0.f, 0.f, 0.f};
            if (i >= 3) {
                w.x = ks[i]; w.y = ks[i - 1]; w.z = ks[i - 2]; w.w = ks[i - 3];
            } else if (i >= 0) {
                w.x = ks[i];
                if (i >= 1) w.y = ks[i - 1];
                if (i >= 2) w.z = ks[i - 2];
            }
            gwinb[tid] = make_uint2(pkbf(w.x, w.y), pkbf(w.z, w.w));
        }
        __syncthreads();

        const int cmax = min(SC, wlmax - s0 + 1);   // wave-uniform, mult of 32
        for (int c = 0; c < cmax; c += 32) {
            // ---- loads first (independent) ----
            bf16x8 av0 = {}, av1 = {};
            if (quad == 0) {
                av0 = *(const bf16x8*)&vT[wb][c + lq][0];
                av1 = *(const bf16x8*)&vT[wb][c + 16 + lq][0];
            }
            const int ge = ebase - c;
            uint2 g10;
            if (gfirst) { g10 = gwinb[ge + 16]; gfirst = false; }
            else        g10 = g10c;
            const uint2 g00 = gwinb[ge];        // S00 & S11
            const uint2 g01 = gwinb[ge - 16];   // S01
            g10c = g01;                         // next iter's g10
            // mfma2 A operand: x2 in pi-permuted k-order
            const bf16x8 ax = *(const bf16x8*)&x2T[wb][lq & 7][c + 8 * quad];

            // ---- mfma1 x4: S^T, 2 m-chunks x 2 l-subtiles ----
            const f32x4 Z = {0.f, 0.f, 0.f, 0.f};
            const f32x4 S00 = __builtin_amdgcn_mfma_f32_16x16x32_bf16(av0, xf0, Z, 0, 0, 0);
            const f32x4 S01 = __builtin_amdgcn_mfma_f32_16x16x32_bf16(av1, xf0, Z, 0, 0, 0);
            const f32x4 S10 = __builtin_amdgcn_mfma_f32_16x16x32_bf16(av0, xf1, Z, 0, 0, 0);
            const f32x4 S11 = __builtin_amdgcn_mfma_f32_16x16x32_bf16(av1, xf1, Z, 0, 0, 0);

            // ---- gate via packed bf16 (cvt_pk + pk_mul), B-frags in regs ----
            U8 p0, p1;
            p0.u[0] = gmul(S00[0], S00[1], g00.x);
            p0.u[1] = gmul(S00[2], S00[3], g00.y);
            p0.u[2] = gmul(S01[0], S01[1], g01.x);
            p0.u[3] = gmul(S01[2], S01[3], g01.y);
            p1.u[0] = gmul(S10[0], S10[1], g10.x);
            p1.u[1] = gmul(S10[2], S10[3], g10.y);
            p1.u[2] = gmul(S11[0], S11[1], g00.x);
            p1.u[3] = gmul(S11[2], S11[3], g00.y);

            // ---- mfma2: O^T += x2 . P^T, full K=32 ----
            acc0 = __builtin_amdgcn_mfma_f32_16x16x32_bf16(ax, p0.v, acc0, 0, 0, 0);
            acc1 = __builtin_amdgcn_mfma_f32_16x16x32_bf16(ax, p1.v, acc1, 0, 0, 0);
        }
    }

    // ---------- epilogue: O^T layout: lane (quad,lq): d2 = 4*quad+r, l = lq ----
    if (quad < 2) {
        const int d2b = 4 * quad;
        const int lA  = wl0 + lq;                 // subtile-0 l; subtile-1 = +16
        const float sb0 = sbuf[wb][(wv & 1) * 32 + lq];
        const float sb1 = sbuf[wb][(wv & 1) * 32 + 16 + lq];
#pragma unroll
        for (int r = 0; r < 4; ++r) {
            const int ro = baseb + (d2b + r) * L + lA;
            out[ro]      = acc0[r] + x2[ro]      * sb0;
            out[ro + 16] = acc1[r] + x2[ro + 16] * sb1;
        }
    }
}

extern "C" void kernel_launch(void* const* d_in, const int* in_sizes, int n_in,
                              void* d_out, int out_size, void* d_ws, size_t ws_size,
                              hipStream_t stream) {
    const float* v    = (const float*)d_in[0];
    const float* k    = (const float*)d_in[1];
    const float* bias = (const float*)d_in[2];
    const float* x1   = (const float*)d_in[3];
    const float* x2   = (const float*)d_in[4];
    float* out = (float*)d_out;

    const int D = in_sizes[2];            // 1024
    const int H = D / NHd;                // 128
    const int L = in_sizes[1] / H;        // 2048
    const int B = in_sizes[0] / (D * L);  // 2

    dim3 grid(H, L / 64);
    hyena_mfma8_kernel<<<grid, 256, 0, stream>>>(v, k, bias, x1, x2, out, B, H, L);
}

// Round 9
// 153.497 us; speedup vs baseline: 1.1975x; 1.1778x over previous
//
#include <hip/hip_runtime.h>
#include <stdint.h>

// Multi-head Hyena conv, MFMA flash-attention form, round 9:
//   S^T[m][l] = sum_d1 v[d1,m]*x1[d1,l]       mfma 16x16x32 (K=8 valid)
//   P[l][m]   = S * k[l-m]   (sliding f32x4 gate window, zero => causal)
//   O^T[d2][l] += x2 . P^T                    mfma 16x16x32 (full K=32)
// Round-9: round-6 structure (proven 90.8us) + gating via v_pk_mul_f32
// (float2 vector mul) and single-v_perm truncation pack: 40 -> 16 VALU
// inst/unit. NO HIP bf16 library calls (round 7/8 showed __hmul2 /
// __float22bfloat162_rn are software-emulated: +22us VALU).
// P is truncation-rounded (bias ~5e-4/elem, absmax <= ~1.0 vs thr 1.78);
// v/x1/x2/gates keep RNE rounding at staging.
// Shapes fixed by setup: B=2, D=1024, L=2048, NH=8, H=128.

typedef __attribute__((ext_vector_type(8))) short bf16x8;
typedef __attribute__((ext_vector_type(4))) float f32x4;
typedef __attribute__((ext_vector_type(2))) float f32x2;

#define NHd  8
#define SC   128     // m superchunk staged in LDS
#define GW   192     // gate window entries: l-m spans [l0b-s0-127, l0b-s0+63]

static __device__ __forceinline__ uint32_t pkbf(float a, float b) {
    // RNE-ish pack {bf16(a) lo, bf16(b) hi}; +0x8000 rounds (ties away)
    const uint32_t ua = __float_as_uint(a) + 0x8000u;
    const uint32_t ub = __float_as_uint(b) + 0x8000u;
    return __builtin_amdgcn_perm(ub, ua, 0x07060302u);
}

static __device__ __forceinline__ uint32_t pktr(f32x2 p) {
    // truncation pack: upper 16 bits of each f32 -> {lo,hi} bf16 word (1 v_perm)
    union { f32x2 f; uint32_t u[2]; } c; c.f = p;
    return __builtin_amdgcn_perm(c.u[1], c.u[0], 0x07060302u);
}

// gate two S values by two k values: v_pk_mul_f32 + v_perm (2 inst)
static __device__ __forceinline__ uint32_t gmul2(f32x2 s, f32x2 g) {
    return pktr(s * g);
}

union U8 { uint32_t u[4]; bf16x8 v; uint4 q; };

__global__ __launch_bounds__(256, 6) void hyena_mfma9_kernel(
    const float* __restrict__ v, const float* __restrict__ kf,
    const float* __restrict__ bias, const float* __restrict__ x1,
    const float* __restrict__ x2, float* __restrict__ out,
    int B, int H, int L)
{
    __shared__ __align__(16) float  ks[2048];           // raw k[h,:] prefix
    __shared__ __align__(16) float4 gwin[GW];           // sliding gate window
    __shared__ __align__(16) ushort vT[2][SC][NHd];     // [b][m][d1] bf16
    __shared__ __align__(16) ushort x2T[2][NHd][136];   // [b][d2][pi(m)] bf16
    __shared__ float sbuf[2][64];                       // skip gate per (b,l)

    const int tid  = threadIdx.x;
    const int h    = blockIdx.x;
    const int l0b  = ((int)gridDim.y - 1 - (int)blockIdx.y) * 64;  // big-l first
    const int nk   = l0b + 64;

    const int lane = tid & 63, wv = tid >> 6;
    const int lq   = lane & 15, quad = lane >> 4;
    const int wb   = wv >> 1;               // batch handled by this wave
    const int wl0  = l0b + (wv & 1) * 32;   // wave's 32-l range start
    const int baseb = (wb * H + h) * NHd * L;

    // ---------- prologue ----------
    for (int i = tid; i < nk; i += 256) ks[i] = kf[h * L + i];

    // xf fragments (mfma1 B operand) straight from global, packed in registers
    bf16x8 xf0 = {}, xf1 = {};
    if (quad == 0) {
        float a0[NHd], a1[NHd];
#pragma unroll
        for (int d1 = 0; d1 < NHd; ++d1) {
            a0[d1] = x1[baseb + d1 * L + wl0 + lq];
            a1[d1] = x1[baseb + d1 * L + wl0 + 16 + lq];
        }
        U8 u0, u1;
#pragma unroll
        for (int j = 0; j < 4; ++j) {
            u0.u[j] = pkbf(a0[2 * j], a0[2 * j + 1]);
            u1.u[j] = pkbf(a1[2 * j], a1[2 * j + 1]);
        }
        xf0 = u0.v; xf1 = u1.v;
    }

    // skip-term gate, both b (threads 0..127)
    if (tid < 128) {
        const int bb = tid >> 6, l = tid & 63;
        const int bs = (bb * H + h) * NHd * L;
        float s = 0.f;
#pragma unroll
        for (int d1 = 0; d1 < NHd; ++d1)
            s += bias[h * NHd + d1] * x1[bs + d1 * L + l0b + l]
                                    * v [bs + d1 * L + l0b + l];
        sbuf[bb][l] = s;
    }

    f32x4 acc0 = {0.f, 0.f, 0.f, 0.f}, acc1 = {0.f, 0.f, 0.f, 0.f};
    const int wlmax = wl0 + 31;
    // in-loop gate window coordinate (s0-independent): e = ebase - c (+/-16)
    const int ebase = 127 + (wv & 1) * 32 + lq - 4 * quad;

    bool gfirst = true;
    float4 g10c = {0.f, 0.f, 0.f, 0.f};    // carried: g10(c+32) == g01(c)

    for (int s0 = 0; s0 < nk; s0 += SC) {
        __syncthreads();   // protects gwin/vT/x2T from previous iter's readers
        {   // stage vT [b][m][d1] and x2T [b][d2][pi(m)], bf16 via pkbf
            const int bb = tid >> 7, row = tid & 127;
            const int bs = (bb * H + h) * NHd * L;
            const float* vp = v + bs + s0 + row;
            float f[NHd];
#pragma unroll
            for (int d1 = 0; d1 < NHd; ++d1) f[d1] = vp[d1 * L];
            *(uint4*)&vT[bb][row][0] = make_uint4(
                pkbf(f[0], f[1]), pkbf(f[2], f[3]),
                pkbf(f[4], f[5]), pkbf(f[6], f[7]));

            // x2T in pi-permuted order: within each 32-m group, value at m
            // goes to pos 8*((m&15)>>2) + (m&3) + 4*(m>>4)
            const int d2 = row >> 4, ms = (row & 15) * 8;
            const int G = ms & ~31;                       // 32-group base
            const int o = ms & 31;                        // 0,8,16,24
            const int pa = ((o >> 2) & 3) * 8 + (o >> 4) * 4;
            const float* xp = x2 + bs + d2 * L + s0 + ms;
            const float4 q0 = *(const float4*)xp;
            const float4 q1 = *(const float4*)(xp + 4);
            *(uint2*)&x2T[bb][d2][G + pa] =
                make_uint2(pkbf(q0.x, q0.y), pkbf(q0.z, q0.w));
            *(uint2*)&x2T[bb][d2][G + pa + 8] =
                make_uint2(pkbf(q1.x, q1.y), pkbf(q1.z, q1.w));
        }
        // rebuild sliding gate window: gwin[e] = {k[i],k[i-1],k[i-2],k[i-3]},
        // i = l0b - s0 - 127 + e; i<0 components -> 0 (causality)
        if (tid < GW - 1) {
            const int i = l0b - s0 - 127 + tid;
            float4 w = {0.f, 0.f, 0.f, 0.f};
            if (i >= 3) {
                w.x = ks[i]; w.y = ks[i - 1]; w.z = ks[i - 2]; w.w = ks[i - 3];
            } else if (i >= 0) {
                w.x = ks[i];
                if (i >= 1) w.y = ks[i - 1];
                if (i >= 2) w.z = ks[i - 2];
            }
            gwin[tid] = w;
        }
        __syncthreads();

        const int cmax = min(SC, wlmax - s0 + 1);   // wave-uniform, mult of 32
        for (int c = 0; c < cmax; c += 32) {
            // ---- loads first (independent) ----
            bf16x8 av0 = {}, av1 = {};
            if (quad == 0) {
                av0 = *(const bf16x8*)&vT[wb][c + lq][0];
                av1 = *(const bf16x8*)&vT[wb][c + 16 + lq][0];
            }
            const int ge = ebase - c;
            float4 g10;
            if (gfirst) { g10 = *(const float4*)&gwin[ge + 16]; gfirst = false; }
            else        g10 = g10c;
            const float4 g00 = *(const float4*)&gwin[ge];        // S00 & S11
            const float4 g01 = *(const float4*)&gwin[ge - 16];   // S01
            g10c = g01;                                          // next iter's g10
            // mfma2 A operand: x2 in pi-permuted k-order
            const bf16x8 ax = *(const bf16x8*)&x2T[wb][lq & 7][c + 8 * quad];

            // ---- mfma1 x4: S^T, 2 m-chunks x 2 l-subtiles ----
            const f32x4 Z = {0.f, 0.f, 0.f, 0.f};
            const f32x4 S00 = __builtin_amdgcn_mfma_f32_16x16x32_bf16(av0, xf0, Z, 0, 0, 0);
            const f32x4 S01 = __builtin_amdgcn_mfma_f32_16x16x32_bf16(av1, xf0, Z, 0, 0, 0);
            const f32x4 S10 = __builtin_amdgcn_mfma_f32_16x16x32_bf16(av0, xf1, Z, 0, 0, 0);
            const f32x4 S11 = __builtin_amdgcn_mfma_f32_16x16x32_bf16(av1, xf1, Z, 0, 0, 0);

            // ---- gate via v_pk_mul_f32 + v_perm trunc-pack, B-frags in regs ----
            U8 p0, p1;
            p0.u[0] = gmul2((f32x2){S00[0], S00[1]}, (f32x2){g00.x, g00.y});
            p0.u[1] = gmul2((f32x2){S00[2], S00[3]}, (f32x2){g00.z, g00.w});
            p0.u[2] = gmul2((f32x2){S01[0], S01[1]}, (f32x2){g01.x, g01.y});
            p0.u[3] = gmul2((f32x2){S01[2], S01[3]}, (f32x2){g01.z, g01.w});
            p1.u[0] = gmul2((f32x2){S10[0], S10[1]}, (f32x2){g10.x, g10.y});
            p1.u[1] = gmul2((f32x2){S10[2], S10[3]}, (f32x2){g10.z, g10.w});
            p1.u[2] = gmul2((f32x2){S11[0], S11[1]}, (f32x2){g00.x, g00.y});
            p1.u[3] = gmul2((f32x2){S11[2], S11[3]}, (f32x2){g00.z, g00.w});

            // ---- mfma2: O^T += x2 . P^T, full K=32 ----
            acc0 = __builtin_amdgcn_mfma_f32_16x16x32_bf16(ax, p0.v, acc0, 0, 0, 0);
            acc1 = __builtin_amdgcn_mfma_f32_16x16x32_bf16(ax, p1.v, acc1, 0, 0, 0);
        }
    }

    // ---------- epilogue: O^T layout: lane (quad,lq): d2 = 4*quad+r, l = lq ----
    if (quad < 2) {
        const int d2b = 4 * quad;
        const int lA  = wl0 + lq;                 // subtile-0 l; subtile-1 = +16
        const float sb0 = sbuf[wb][(wv & 1) * 32 + lq];
        const float sb1 = sbuf[wb][(wv & 1) * 32 + 16 + lq];
#pragma unroll
        for (int r = 0; r < 4; ++r) {
            const int ro = baseb + (d2b + r) * L + lA;
            out[ro]      = acc0[r] + x2[ro]      * sb0;
            out[ro + 16] = acc1[r] + x2[ro + 16] * sb1;
        }
    }
}

extern "C" void kernel_launch(void* const* d_in, const int* in_sizes, int n_in,
                              void* d_out, int out_size, void* d_ws, size_t ws_size,
                              hipStream_t stream) {
    const float* v    = (const float*)d_in[0];
    const float* k    = (const float*)d_in[1];
    const float* bias = (const float*)d_in[2];
    const float* x1   = (const float*)d_in[3];
    const float* x2   = (const float*)d_in[4];
    float* out = (float*)d_out;

    const int D = in_sizes[2];            // 1024
    const int H = D / NHd;                // 128
    const int L = in_sizes[1] / H;        // 2048
    const int B = in_sizes[0] / (D * L);  // 2

    dim3 grid(H, L / 64);
    hyena_mfma9_kernel<<<grid, 256, 0, stream>>>(v, k, bias, x1, x2, out, B, H, L);
}

// Round 10
// 151.491 us; speedup vs baseline: 1.2134x; 1.0132x over previous
//
#include <hip/hip_runtime.h>
#include <stdint.h>

// Multi-head Hyena conv, MFMA flash-attention form, round 10:
//   S^T[m][l] = sum_d1 v[d1,m]*x1[d1,l]       mfma 16x16x32 (K=8 valid)
//   P[l][m]   = S * k[l-m]   (sliding f32x4 gate window, zero => causal)
//   O^T[d2][l] += x2 . P^T                    mfma 16x16x32 (full K=32)
// Round-10: wave handles 64 l (4 subtiles, was 32/2); block covers 128 l
// x both batches. Amortizes av/ax reads, staging, and loop overhead 2x per
// unit. 5-deep gate register file (g0..g4), 2 LDS gate reads/iter, carry
// chains across superchunk boundaries. (256,5): ~100 VGPR, no spill
// (round-7 lesson: tighter bounds => scratch spills, WRITE_SIZE blows up).
// Gating stays v_pk_mul_f32 + v_perm trunc-pack (round-9 proven).
// Shapes fixed by setup: B=2, D=1024, L=2048, NH=8, H=128.

typedef __attribute__((ext_vector_type(8))) short bf16x8;
typedef __attribute__((ext_vector_type(4))) float f32x4;
typedef __attribute__((ext_vector_type(2))) float f32x2;

#define NHd  8
#define SC   128     // m superchunk staged in LDS
#define GW   256     // gate window: l-m spans [l0b-s0-127, l0b-s0+127]

static __device__ __forceinline__ uint32_t pkbf(float a, float b) {
    // RNE-ish pack {bf16(a) lo, bf16(b) hi}; +0x8000 rounds (ties away)
    const uint32_t ua = __float_as_uint(a) + 0x8000u;
    const uint32_t ub = __float_as_uint(b) + 0x8000u;
    return __builtin_amdgcn_perm(ub, ua, 0x07060302u);
}

static __device__ __forceinline__ uint32_t pktr(f32x2 p) {
    // truncation pack: upper 16 bits of each f32 -> {lo,hi} bf16 (1 v_perm)
    union { f32x2 f; uint32_t u[2]; } c; c.f = p;
    return __builtin_amdgcn_perm(c.u[1], c.u[0], 0x07060302u);
}

// gate two S values by two k values: v_pk_mul_f32 + v_perm (2 inst)
static __device__ __forceinline__ uint32_t gmul2(f32x2 s, f32x2 g) {
    return pktr(s * g);
}

union U8 { uint32_t u[4]; bf16x8 v; uint4 q; };

__global__ __launch_bounds__(256, 5) void hyena_mfma10_kernel(
    const float* __restrict__ v, const float* __restrict__ kf,
    const float* __restrict__ bias, const float* __restrict__ x1,
    const float* __restrict__ x2, float* __restrict__ out,
    int B, int H, int L)
{
    __shared__ __align__(16) float  ks[2048];           // raw k[h,:] prefix
    __shared__ __align__(16) float4 gwin[GW];           // sliding gate window
    __shared__ __align__(16) ushort vT[2][SC][NHd];     // [b][m][d1] bf16
    __shared__ __align__(16) ushort x2T[2][NHd][136];   // [b][d2][pi(m)] bf16
    __shared__ float sbuf[2][128];                      // skip gate per (b,l)

    const int tid  = threadIdx.x;
    const int h    = blockIdx.x;
    const int l0b  = ((int)gridDim.y - 1 - (int)blockIdx.y) * 128; // big-l first
    const int nk   = l0b + 128;

    const int lane = tid & 63, wv = tid >> 6;
    const int lq   = lane & 15, quad = lane >> 4;
    const int wb   = wv & 1;                // batch handled by this wave
    const int wseg = wv >> 1;               // which 64-l half of the block
    const int wl0  = l0b + wseg * 64;       // wave's 64-l range start
    const int baseb = (wb * H + h) * NHd * L;

    // ---------- prologue ----------
    for (int i = tid; i < nk; i += 256) ks[i] = kf[h * L + i];

    // xf fragments (mfma1 B operand) for 4 l-subtiles, packed in registers
    bf16x8 xf[4] = {};
    if (quad == 0) {
#pragma unroll
        for (int j = 0; j < 4; ++j) {
            float a0[NHd];
#pragma unroll
            for (int d1 = 0; d1 < NHd; ++d1)
                a0[d1] = x1[baseb + d1 * L + wl0 + 16 * j + lq];
            U8 u0;
#pragma unroll
            for (int t = 0; t < 4; ++t) u0.u[t] = pkbf(a0[2 * t], a0[2 * t + 1]);
            xf[j] = u0.v;
        }
    }

    // skip-term gate, both b, 128 l (all 256 threads)
    {
        const int bb = tid >> 7, l = tid & 127;
        const int bs = (bb * H + h) * NHd * L;
        float s = 0.f;
#pragma unroll
        for (int d1 = 0; d1 < NHd; ++d1)
            s += bias[h * NHd + d1] * x1[bs + d1 * L + l0b + l]
                                    * v [bs + d1 * L + l0b + l];
        sbuf[bb][l] = s;
    }

    f32x4 acc[4];
#pragma unroll
    for (int j = 0; j < 4; ++j) acc[j] = (f32x4){0.f, 0.f, 0.f, 0.f};

    const int wlmax = wl0 + 63;
    // gate window coordinate (s0-independent): e = ebase - c
    const int ebase = 127 + wseg * 64 + lq - 4 * quad;

    bool gfirst = true;
    float4 g0, g1, g2, g3, g4;   // 5-deep gate file; carries across s0 too

    for (int s0 = 0; s0 < nk; s0 += SC) {
        __syncthreads();   // protects gwin/vT/x2T from previous iter's readers
        {   // stage vT [b][m][d1] and x2T [b][d2][pi(m)], bf16 via pkbf
            const int bb = tid >> 7, row = tid & 127;
            const int bs = (bb * H + h) * NHd * L;
            const float* vp = v + bs + s0 + row;
            float f[NHd];
#pragma unroll
            for (int d1 = 0; d1 < NHd; ++d1) f[d1] = vp[d1 * L];
            *(uint4*)&vT[bb][row][0] = make_uint4(
                pkbf(f[0], f[1]), pkbf(f[2], f[3]),
                pkbf(f[4], f[5]), pkbf(f[6], f[7]));

            // x2T in pi-permuted order: within each 32-m group, value at m
            // goes to pos 8*((m&15)>>2) + (m&3) + 4*(m>>4)
            const int d2 = row >> 4, ms = (row & 15) * 8;
            const int G = ms & ~31;                       // 32-group base
            const int o = ms & 31;                        // 0,8,16,24
            const int pa = ((o >> 2) & 3) * 8 + (o >> 4) * 4;
            const float* xp = x2 + bs + d2 * L + s0 + ms;
            const float4 q0 = *(const float4*)xp;
            const float4 q1 = *(const float4*)(xp + 4);
            *(uint2*)&x2T[bb][d2][G + pa] =
                make_uint2(pkbf(q0.x, q0.y), pkbf(q0.z, q0.w));
            *(uint2*)&x2T[bb][d2][G + pa + 8] =
                make_uint2(pkbf(q1.x, q1.y), pkbf(q1.z, q1.w));
        }
        // rebuild sliding gate window: gwin[e] = {k[i],k[i-1],k[i-2],k[i-3]},
        // i = l0b - s0 - 127 + e; i<0 components -> 0 (causality).
        // entry 255 never read (max read index 254) -> skip.
        if (tid < GW - 1) {
            const int i = l0b - s0 - 127 + tid;
            float4 w = {0.f, 0.f, 0.f, 0.f};
            if (i >= 3) {
                w.x = ks[i]; w.y = ks[i - 1]; w.z = ks[i - 2]; w.w = ks[i - 3];
            } else if (i >= 0) {
                w.x = ks[i];
                if (i >= 1) w.y = ks[i - 1];
                if (i >= 2) w.z = ks[i - 2];
            }
            gwin[tid] = w;
        }
        __syncthreads();

        // wave-uniform trip count, multiple of 32 (wseg0: 64 at diagonal)
        const int cmax = min(SC, wlmax - s0 + 1);
        for (int c = 0; c < cmax; c += 32) {
            const int e = ebase - c;

            // ---- loads first (independent) ----
            bf16x8 av0 = {}, av1 = {};
            if (quad == 0) {
                av0 = *(const bf16x8*)&vT[wb][c + lq][0];
                av1 = *(const bf16x8*)&vT[wb][c + 16 + lq][0];
            }
            // gate file: subtile j: lo = g(e+16j), hi = g(e+16j-16)
            if (gfirst) {
                g4 = *(const float4*)&gwin[e + 48];
                g3 = *(const float4*)&gwin[e + 32];
                g2 = *(const float4*)&gwin[e + 16];
                gfirst = false;
            } else { g4 = g2; g3 = g1; g2 = g0; }
            g1 = *(const float4*)&gwin[e];
            g0 = *(const float4*)&gwin[e - 16];
            const bf16x8 ax = *(const bf16x8*)&x2T[wb][lq & 7][c + 8 * quad];

            const f32x4 Z = {0.f, 0.f, 0.f, 0.f};
            // ---- subtile pair 0,1 ----
            {
                const f32x4 Sa0 = __builtin_amdgcn_mfma_f32_16x16x32_bf16(av0, xf[0], Z, 0, 0, 0);
                const f32x4 Sa1 = __builtin_amdgcn_mfma_f32_16x16x32_bf16(av1, xf[0], Z, 0, 0, 0);
                const f32x4 Sb0 = __builtin_amdgcn_mfma_f32_16x16x32_bf16(av0, xf[1], Z, 0, 0, 0);
                const f32x4 Sb1 = __builtin_amdgcn_mfma_f32_16x16x32_bf16(av1, xf[1], Z, 0, 0, 0);
                U8 p;
                p.u[0] = gmul2((f32x2){Sa0[0], Sa0[1]}, (f32x2){g1.x, g1.y});
                p.u[1] = gmul2((f32x2){Sa0[2], Sa0[3]}, (f32x2){g1.z, g1.w});
                p.u[2] = gmul2((f32x2){Sa1[0], Sa1[1]}, (f32x2){g0.x, g0.y});
                p.u[3] = gmul2((f32x2){Sa1[2], Sa1[3]}, (f32x2){g0.z, g0.w});
                acc[0] = __builtin_amdgcn_mfma_f32_16x16x32_bf16(ax, p.v, acc[0], 0, 0, 0);
                p.u[0] = gmul2((f32x2){Sb0[0], Sb0[1]}, (f32x2){g2.x, g2.y});
                p.u[1] = gmul2((f32x2){Sb0[2], Sb0[3]}, (f32x2){g2.z, g2.w});
                p.u[2] = gmul2((f32x2){Sb1[0], Sb1[1]}, (f32x2){g1.x, g1.y});
                p.u[3] = gmul2((f32x2){Sb1[2], Sb1[3]}, (f32x2){g1.z, g1.w});
                acc[1] = __builtin_amdgcn_mfma_f32_16x16x32_bf16(ax, p.v, acc[1], 0, 0, 0);
            }
            // ---- subtile pair 2,3 ----
            {
                const f32x4 Sc0 = __builtin_amdgcn_mfma_f32_16x16x32_bf16(av0, xf[2], Z, 0, 0, 0);
                const f32x4 Sc1 = __builtin_amdgcn_mfma_f32_16x16x32_bf16(av1, xf[2], Z, 0, 0, 0);
                const f32x4 Sd0 = __builtin_amdgcn_mfma_f32_16x16x32_bf16(av0, xf[3], Z, 0, 0, 0);
                const f32x4 Sd1 = __builtin_amdgcn_mfma_f32_16x16x32_bf16(av1, xf[3], Z, 0, 0, 0);
                U8 p;
                p.u[0] = gmul2((f32x2){Sc0[0], Sc0[1]}, (f32x2){g3.x, g3.y});
                p.u[1] = gmul2((f32x2){Sc0[2], Sc0[3]}, (f32x2){g3.z, g3.w});
                p.u[2] = gmul2((f32x2){Sc1[0], Sc1[1]}, (f32x2){g2.x, g2.y});
                p.u[3] = gmul2((f32x2){Sc1[2], Sc1[3]}, (f32x2){g2.z, g2.w});
                acc[2] = __builtin_amdgcn_mfma_f32_16x16x32_bf16(ax, p.v, acc[2], 0, 0, 0);
                p.u[0] = gmul2((f32x2){Sd0[0], Sd0[1]}, (f32x2){g4.x, g4.y});
                p.u[1] = gmul2((f32x2){Sd0[2], Sd0[3]}, (f32x2){g4.z, g4.w});
                p.u[2] = gmul2((f32x2){Sd1[0], Sd1[1]}, (f32x2){g3.x, g3.y});
                p.u[3] = gmul2((f32x2){Sd1[2], Sd1[3]}, (f32x2){g3.z, g3.w});
                acc[3] = __builtin_amdgcn_mfma_f32_16x16x32_bf16(ax, p.v, acc[3], 0, 0, 0);
            }
        }
    }

    // ---------- epilogue: O^T layout: lane (quad,lq): d2 = 4*quad+r, l = lq ----
    if (quad < 2) {
#pragma unroll
        for (int j = 0; j < 4; ++j) {
            const int lA  = wl0 + 16 * j + lq;
            const float sb = sbuf[wb][wseg * 64 + 16 * j + lq];
#pragma unroll
            for (int r = 0; r < 4; ++r) {
                const int ro = baseb + (4 * quad + r) * L + lA;
                out[ro] = acc[j][r] + x2[ro] * sb;
            }
        }
    }
}

extern "C" void kernel_launch(void* const* d_in, const int* in_sizes, int n_in,
                              void* d_out, int out_size, void* d_ws, size_t ws_size,
                              hipStream_t stream) {
    const float* v    = (const float*)d_in[0];
    const float* k    = (const float*)d_in[1];
    const float* bias = (const float*)d_in[2];
    const float* x1   = (const float*)d_in[3];
    const float* x2   = (const float*)d_in[4];
    float* out = (float*)d_out;

    const int D = in_sizes[2];            // 1024
    const int H = D / NHd;                // 128
    const int L = in_sizes[1] / H;        // 2048
    const int B = in_sizes[0] / (D * L);  // 2

    dim3 grid(H, L / 128);
    hyena_mfma10_kernel<<<grid, 256, 0, stream>>>(v, k, bias, x1, x2, out, B, H, L);
}